// Round 4
// baseline (283.454 us; speedup 1.0000x reference)
//
#include <hip/hip_runtime.h>
#include <math.h>

#define S_LEN 262144
#define N 128
#define BR 64
#define TPB 256
#define NT (S_LEN / BR)   // 4096 tiles
#define GRID 1024         // 4 tiles per block

typedef __attribute__((ext_vector_type(8))) short bf16x8;
typedef __attribute__((ext_vector_type(4))) float f32x4;

__device__ __forceinline__ unsigned short f2bf(float x) {
    unsigned b = __float_as_uint(x);
    b = (b + 0x7FFF + ((b >> 16) & 1)) >> 16;   // RNE to bf16
    return (unsigned short)b;
}
__device__ __forceinline__ float bf2f(unsigned short u) {
    return __uint_as_float((unsigned)u << 16);
}
// pack2: low16 = bf16_rhu(x), high16 = bf16_rhu(y) in one dword (2 add + 1 perm)
__device__ __forceinline__ unsigned pack2bf(float x, float y) {
    return __builtin_amdgcn_perm(__float_as_uint(y) + 0x8000u,
                                 __float_as_uint(x) + 0x8000u, 0x07060302u);
}
__device__ __forceinline__ float wave_reduce(float v) {
    #pragma unroll
    for (int off = 32; off > 0; off >>= 1) v += __shfl_down(v, off, 64);
    return v;
}

// M = W_K^T @ W_Q (128x128) fp32; emit bf16 in MFMA-B-fragment order.
// l1 = sum(sigmoid(M)) -> out[1].
__global__ void mk_kernel(const float* __restrict__ WQ, const float* __restrict__ WK,
                          unsigned short* __restrict__ fragB, float* __restrict__ out) {
    const int i = blockIdx.x;   // M row (k of main GEMM)
    const int j = threadIdx.x;  // M col
    float acc = 0.f;
    #pragma unroll 8
    for (int r = 0; r < N; ++r) acc = fmaf(WK[r * N + i], WQ[r * N + j], acc);

    const int kk = i >> 5, q = (i >> 3) & 3, jj = i & 7;
    const int ct = j >> 4, n15 = j & 15;
    fragB[((kk * 8 + ct) * 64 + (q * 16 + n15)) * 8 + jj] = f2bf(acc);

    float sg = fabsf(1.0f / (1.0f + __expf(-acc)));
    float ws = wave_reduce(sg);
    __shared__ float red[2];
    if ((j & 63) == 0) red[j >> 6] = ws;
    __syncthreads();
    if (j == 0) atomicAdd(&out[1], red[0] + red[1]);
}

__global__ __launch_bounds__(TPB, 3) void main_kernel(
    const float* __restrict__ In, const unsigned short* __restrict__ fragB,
    float* __restrict__ out, float inv_denom) {
    __shared__ unsigned short sA[65][136];   // 65 rows x 128 bf16 (row 64 = s+1 boundary)
    __shared__ float sPartF[64][33];
    __shared__ float sPart[64][4];
    __shared__ float sRed[TPB / 64];

    const int tid = threadIdx.x;
    const int w = tid >> 6, lane = tid & 63;
    const int q = lane >> 4, n15 = lane & 15;

    // B fragments for this wave's 32 cols (L2-hot), held for whole kernel
    bf16x8 bF[2][4];
    #pragma unroll
    for (int c = 0; c < 2; ++c)
        #pragma unroll
        for (int kk = 0; kk < 4; ++kk)
            bF[c][kk] = *(const bf16x8*)&fragB[((kk * 8 + (w * 2 + c)) * 64 + lane) * 8];

    float4 buf0[8], buf1[8], x0, x1;
    float lsum = 0.f;

    auto issue = [&](float4 (&b)[8], float4& x, int tile) {
        const long r0 = (long)tile * BR;
        #pragma unroll
        for (int t = 0; t < 8; ++t) {
            const int qq = tid + t * TPB;
            const int r = qq >> 5, c4 = (qq & 31) << 2;
            b[t] = *(const float4*)&In[(r0 + r) * N + c4];
        }
        if (tid < 32) {
            long rX = r0 + 64; if (rX > S_LEN - 1) rX = S_LEN - 1;
            x = *(const float4*)&In[rX * N + (tid << 2)];
        }
    };

    auto compute = [&](float4 (&b)[8], float4& x, int tile) {
        const long r0 = (long)tile * BR;
        // convert -> LDS bf16 + fp32 rowsum partials
        #pragma unroll
        for (int t = 0; t < 8; ++t) {
            const int qq = tid + t * TPB;
            const int r = qq >> 5, c4 = (qq & 31) << 2;
            uint2 pk = make_uint2(pack2bf(b[t].x, b[t].y), pack2bf(b[t].z, b[t].w));
            *(uint2*)&sA[r][c4] = pk;
            sPartF[r][qq & 31] = b[t].x + b[t].y + b[t].z + b[t].w;
        }
        if (tid < 32)
            *(uint2*)&sA[64][tid << 2] = make_uint2(pack2bf(x.x, x.y), pack2bf(x.z, x.w));
        __syncthreads();

        // rowsum stage 2
        {
            const int r = tid >> 2, sg0 = (tid & 3) << 3;
            float s = 0.f;
            #pragma unroll
            for (int e = 0; e < 8; ++e) s += sPartF[r][sg0 + e];
            sPart[r][tid & 3] = s;
        }

        // MFMA: 4 row-tiles x 2 col-tiles, K=128
        f32x4 acc[4][2];
        #pragma unroll
        for (int rt = 0; rt < 4; ++rt)
            #pragma unroll
            for (int c = 0; c < 2; ++c) acc[rt][c] = (f32x4){0.f, 0.f, 0.f, 0.f};
        #pragma unroll
        for (int rt = 0; rt < 4; ++rt) {
            #pragma unroll
            for (int kk = 0; kk < 4; ++kk) {
                bf16x8 a = *(const bf16x8*)&sA[rt * 16 + n15][kk * 32 + q * 8];
                #pragma unroll
                for (int c = 0; c < 2; ++c)
                    acc[rt][c] = __builtin_amdgcn_mfma_f32_16x16x32_bf16(a, bF[c][kk], acc[rt][c], 0, 0, 0);
            }
        }
        __syncthreads();   // sPart ready; acc done

        // epilogue: C/D row = rt*16 + q*4 + reg, col = w*32 + c*16 + n15
        #pragma unroll
        for (int rt = 0; rt < 4; ++rt) {
            #pragma unroll
            for (int reg = 0; reg < 4; ++reg) {
                const int row = rt * 16 + q * 4 + reg;
                const float4 p = *(const float4*)&sPart[row][0];
                const float rs = p.x + p.y + p.z + p.w;
                const long s = r0 + row;
                const bool has = (s < S_LEN - 1);
                #pragma unroll
                for (int c = 0; c < 2; ++c) {
                    const float z = acc[rt][c][reg];
                    const float sp = fmaxf(z, 0.f) + __logf(1.0f + __expf(-fabsf(z)));
                    const float o = sp * rs;
                    if (has) {
                        const int col = w * 32 + c * 16 + n15;
                        const float d = o - bf2f(sA[row + 1][col]);
                        lsum = fmaf(d, d, lsum);
                    }
                }
            }
        }
        __syncthreads();   // protect LDS for next tile's staging
    };

    // software-pipelined grid-stride: issue next tile's loads before computing current
    int t0 = blockIdx.x;
    issue(buf0, x0, t0);
    while (t0 < NT) {
        const int t1 = t0 + GRID;
        if (t1 < NT) issue(buf1, x1, t1);
        compute(buf0, x0, t0);
        t0 = t1;
        if (t0 >= NT) break;
        const int t2 = t0 + GRID;
        if (t2 < NT) issue(buf0, x0, t2);
        compute(buf1, x1, t0);
        t0 = t2;
    }

    const float wsum = wave_reduce(lsum);
    if ((tid & 63) == 0) sRed[w] = wsum;
    __syncthreads();
    if (tid == 0) {
        float t = 0.f;
        #pragma unroll
        for (int w2 = 0; w2 < TPB / 64; ++w2) t += sRed[w2];
        atomicAdd(&out[0], t * inv_denom);
    }
}

extern "C" void kernel_launch(void* const* d_in, const int* in_sizes, int n_in,
                              void* d_out, int out_size, void* d_ws, size_t ws_size,
                              hipStream_t stream) {
    const float* In = (const float*)d_in[0];
    const float* WQ = (const float*)d_in[1];
    const float* WK = (const float*)d_in[2];
    float* out = (float*)d_out;
    unsigned short* fragB = (unsigned short*)d_ws;   // 32 KB

    hipMemsetAsync(d_out, 0, 2 * sizeof(float), stream);
    mk_kernel<<<128, 128, 0, stream>>>(WQ, WK, fragB, out);
    const float inv = (float)(1.0 / ((double)(S_LEN - 1) * (double)N));
    main_kernel<<<GRID, TPB, 0, stream>>>(In, fragB, out, inv);
}

// Round 5
// 215.058 us; speedup vs baseline: 1.3180x; 1.3180x over previous
//
#include <hip/hip_runtime.h>
#include <math.h>

#define S_LEN 262144
#define N 128
#define BR 64
#define TPB 256
#define NT (S_LEN / BR)      // 4096 tiles
#define GRID 1024            // blocks
#define TILES_PER_BLOCK (NT / GRID)   // 4

typedef __attribute__((ext_vector_type(8))) short bf16x8;
typedef __attribute__((ext_vector_type(4))) float f32x4;

__device__ __forceinline__ unsigned short f2bf(float x) {
    unsigned b = __float_as_uint(x);
    b = (b + 0x7FFF + ((b >> 16) & 1)) >> 16;   // RNE to bf16
    return (unsigned short)b;
}
__device__ __forceinline__ float bf2f(unsigned short u) {
    return __uint_as_float((unsigned)u << 16);
}
// low16 = bf16(x), high16 = bf16(y) (round-half-up), 3 VALU ops
__device__ __forceinline__ unsigned pack2bf(float x, float y) {
    return __builtin_amdgcn_perm(__float_as_uint(y) + 0x8000u,
                                 __float_as_uint(x) + 0x8000u, 0x07060302u);
}
__device__ __forceinline__ float wave_reduce(float v) {
    #pragma unroll
    for (int off = 32; off > 0; off >>= 1) v += __shfl_down(v, off, 64);
    return v;
}
// async global->LDS DMA, 16 B per lane; lds dest = uniform base + lane*16
__device__ __forceinline__ void gld16(const float* g, float* l) {
    __builtin_amdgcn_global_load_lds(
        (const __attribute__((address_space(1))) unsigned int*)g,
        (__attribute__((address_space(3))) unsigned int*)l, 16, 0, 0);
}

// M = W_K^T @ W_Q (128x128) fp32; emit bf16 in MFMA-B-fragment order:
//   frag[((kk*8 + ct)*64 + lane)*8 + j] = M[kk*32 + (lane>>4)*8 + j][ct*16 + (lane&15)]
// l1 = sum(sigmoid(M)) -> out[1].
__global__ void mk_kernel(const float* __restrict__ WQ, const float* __restrict__ WK,
                          unsigned short* __restrict__ fragB, float* __restrict__ out) {
    const int i = blockIdx.x;   // M row (k of main GEMM) -- uniform => scalar loads
    const int j = threadIdx.x;  // M col
    float acc = 0.f;
    #pragma unroll 8
    for (int r = 0; r < N; ++r) acc = fmaf(WK[r * N + i], WQ[r * N + j], acc);

    const int kk = i >> 5, q = (i >> 3) & 3, jj = i & 7;
    const int ct = j >> 4, n15 = j & 15;
    fragB[((kk * 8 + ct) * 64 + (q * 16 + n15)) * 8 + jj] = f2bf(acc);

    float sg = fabsf(1.0f / (1.0f + __expf(-acc)));
    float ws = wave_reduce(sg);
    __shared__ float red[2];
    if ((j & 63) == 0) red[j >> 6] = ws;
    __syncthreads();
    if (j == 0) atomicAdd(&out[1], red[0] + red[1]);
}

__global__ __launch_bounds__(TPB, 3) void main_kernel(
    const float* __restrict__ In, const unsigned short* __restrict__ fragB,
    float* __restrict__ out, float inv_denom) {
    __shared__ float F[BR * N];               // 32 KB DMA landing zone (unpadded!)
    __shared__ unsigned short sA[65][136];    // bf16 tile + boundary row, pad 136
    __shared__ float sRed[TPB / 64];

    const int tid = threadIdx.x;
    const int w = tid >> 6, lane = tid & 63;
    const int q = lane >> 4, n15 = lane & 15;

    // B fragments (wave's 32 output cols), held in VGPRs for whole kernel
    bf16x8 bF[2][4];
    #pragma unroll
    for (int c = 0; c < 2; ++c)
        #pragma unroll
        for (int kk = 0; kk < 4; ++kk)
            bF[c][kk] = *(const bf16x8*)&fragB[((kk * 8 + (w * 2 + c)) * 64 + lane) * 8];

    bf16x8 bOne;   // all-ones B fragment: rowsum via MFMA
    #pragma unroll
    for (int e = 0; e < 8; ++e) bOne[e] = (short)0x3F80;

    float lsum = 0.f;
    float4 x;           // boundary row (r0+64), 32 threads x float4
    int tile = blockIdx.x;

    // prologue: issue DMA + boundary load for first tile
    {
        const float* gb = In + (size_t)tile * BR * N;
        #pragma unroll
        for (int j = 0; j < 8; ++j) {
            const int ci = w * 8 + j;                 // 1 KB chunk id, wave-uniform
            gld16(gb + ci * 256 + lane * 4, &F[ci * 256]);
        }
        long rX = (long)tile * BR + BR; if (rX > S_LEN - 1) rX = S_LEN - 1;
        if (tid < 32) x = *(const float4*)&In[rX * N + (tid << 2)];
    }

    for (int it = 0; it < TILES_PER_BLOCK; ++it) {
        asm volatile("s_waitcnt vmcnt(0)" ::: "memory");  // this wave's DMA done
        __syncthreads();                                  // all waves' DMA done; prev epilogue done

        // repack F (fp32) -> sA (bf16); conflict-free row-major b128 reads
        #pragma unroll
        for (int t = 0; t < 8; ++t) {
            const int qq = tid + t * TPB;
            const int r = qq >> 5, c4 = (qq & 31) << 2;
            const float4 v = *(const float4*)&F[r * N + c4];
            *(uint2*)&sA[r][c4] = make_uint2(pack2bf(v.x, v.y), pack2bf(v.z, v.w));
        }
        if (tid < 32)
            *(uint2*)&sA[64][tid << 2] = make_uint2(pack2bf(x.x, x.y), pack2bf(x.z, x.w));
        __syncthreads();   // sA visible; F fully consumed by all waves

        // prefetch next tile into F; latency hidden behind MFMA+epilogue
        if (it + 1 < TILES_PER_BLOCK) {
            const int nt2 = tile + GRID;
            const float* gb = In + (size_t)nt2 * BR * N;
            #pragma unroll
            for (int j = 0; j < 8; ++j) {
                const int ci = w * 8 + j;
                gld16(gb + ci * 256 + lane * 4, &F[ci * 256]);
            }
            long rX = (long)nt2 * BR + BR; if (rX > S_LEN - 1) rX = S_LEN - 1;
            if (tid < 32) x = *(const float4*)&In[rX * N + (tid << 2)];
        }

        // MFMA: z-tiles + rowsum (ones-B) in one pass over A fragments
        f32x4 acc[4][2], accRS[4];
        #pragma unroll
        for (int rt = 0; rt < 4; ++rt) {
            accRS[rt] = (f32x4){0.f, 0.f, 0.f, 0.f};
            #pragma unroll
            for (int c = 0; c < 2; ++c) acc[rt][c] = (f32x4){0.f, 0.f, 0.f, 0.f};
        }
        #pragma unroll
        for (int rt = 0; rt < 4; ++rt) {
            #pragma unroll
            for (int kk = 0; kk < 4; ++kk) {
                bf16x8 a = *(const bf16x8*)&sA[rt * 16 + n15][kk * 32 + q * 8];
                accRS[rt] = __builtin_amdgcn_mfma_f32_16x16x32_bf16(a, bOne, accRS[rt], 0, 0, 0);
                #pragma unroll
                for (int c = 0; c < 2; ++c)
                    acc[rt][c] = __builtin_amdgcn_mfma_f32_16x16x32_bf16(a, bF[c][kk], acc[rt][c], 0, 0, 0);
            }
        }

        // epilogue: C/D row = rt*16 + q*4 + reg, col = w*32 + c*16 + n15
        // accRS[rt][reg] is exactly rowsum(row) (every col of ones-product equal)
        const long r0 = (long)tile * BR;
        #pragma unroll
        for (int rt = 0; rt < 4; ++rt) {
            #pragma unroll
            for (int reg = 0; reg < 4; ++reg) {
                const int row = rt * 16 + q * 4 + reg;
                const float rs = accRS[rt][reg];
                const long s = r0 + row;
                const bool has = (s < S_LEN - 1);
                #pragma unroll
                for (int c = 0; c < 2; ++c) {
                    const float z = acc[rt][c][reg];
                    const float sp = fmaxf(z, 0.f) + __logf(1.0f + __expf(-fabsf(z)));
                    const float o = sp * rs;
                    if (has) {
                        const int col = w * 32 + c * 16 + n15;
                        const float d = o - bf2f(sA[row + 1][col]);
                        lsum = fmaf(d, d, lsum);
                    }
                }
            }
        }
        tile += GRID;
        // no barrier here: next iteration's waitcnt+syncthreads protects sA/F
    }

    const float wsum = wave_reduce(lsum);
    if ((tid & 63) == 0) sRed[w] = wsum;
    __syncthreads();
    if (tid == 0) {
        float t = 0.f;
        #pragma unroll
        for (int w2 = 0; w2 < TPB / 64; ++w2) t += sRed[w2];
        atomicAdd(&out[0], t * inv_denom);
    }
}

extern "C" void kernel_launch(void* const* d_in, const int* in_sizes, int n_in,
                              void* d_out, int out_size, void* d_ws, size_t ws_size,
                              hipStream_t stream) {
    const float* In = (const float*)d_in[0];
    const float* WQ = (const float*)d_in[1];
    const float* WK = (const float*)d_in[2];
    float* out = (float*)d_out;
    unsigned short* fragB = (unsigned short*)d_ws;   // 32 KB

    hipMemsetAsync(d_out, 0, 2 * sizeof(float), stream);
    mk_kernel<<<128, 128, 0, stream>>>(WQ, WK, fragB, out);
    const float inv = (float)(1.0 / ((double)(S_LEN - 1) * (double)N));
    main_kernel<<<GRID, TPB, 0, stream>>>(In, fragB, out, inv);
}

// Round 6
// 213.772 us; speedup vs baseline: 1.3260x; 1.0060x over previous
//
#include <hip/hip_runtime.h>
#include <math.h>

#define S_LEN 262144
#define N 128
#define BR 64
#define TPB 256
#define NT (S_LEN / BR)      // 4096 tiles
#define GRID 768             // 3 blocks/CU x 256 CUs, all resident

typedef __attribute__((ext_vector_type(8))) short bf16x8;
typedef __attribute__((ext_vector_type(4))) float f32x4;

__device__ __forceinline__ unsigned short f2bf(float x) {
    unsigned b = __float_as_uint(x);
    b = (b + 0x7FFF + ((b >> 16) & 1)) >> 16;   // RNE to bf16
    return (unsigned short)b;
}
__device__ __forceinline__ float bf2f(unsigned short u) {
    return __uint_as_float((unsigned)u << 16);
}
// low16 = bf16(x), high16 = bf16(y) (round-half-up), 3 VALU ops
__device__ __forceinline__ unsigned pack2bf(float x, float y) {
    return __builtin_amdgcn_perm(__float_as_uint(y) + 0x8000u,
                                 __float_as_uint(x) + 0x8000u, 0x07060302u);
}
__device__ __forceinline__ float wave_reduce(float v) {
    #pragma unroll
    for (int off = 32; off > 0; off >>= 1) v += __shfl_down(v, off, 64);
    return v;
}
// async global->LDS DMA, 16 B/lane; LDS dest = wave-uniform base + lane*16
__device__ __forceinline__ void gld16(const float* g, float* l) {
    __builtin_amdgcn_global_load_lds(
        (const __attribute__((address_space(1))) unsigned int*)g,
        (__attribute__((address_space(3))) unsigned int*)l, 16, 0, 0);
}
// waits that do NOT drain the async DMA queue (unlike __syncthreads)
__device__ __forceinline__ void wait_vm0()   { asm volatile("s_waitcnt vmcnt(0)" ::: "memory"); }
__device__ __forceinline__ void wait_lgkm0() { asm volatile("s_waitcnt lgkmcnt(0)" ::: "memory"); }
__device__ __forceinline__ void barrier_raw(){ asm volatile("s_waitcnt lgkmcnt(0)\ns_barrier" ::: "memory"); }

// M = W_K^T @ W_Q (128x128) fp32; emit bf16 in MFMA-B-fragment order:
//   frag[((kk*8 + ct)*64 + lane)*8 + j] = M[kk*32 + (lane>>4)*8 + j][ct*16 + (lane&15)]
// l1 = sum(sigmoid(M)) -> out[1].
__global__ void mk_kernel(const float* __restrict__ WQ, const float* __restrict__ WK,
                          unsigned short* __restrict__ fragB, float* __restrict__ out) {
    const int i = blockIdx.x;   // M row (k of main GEMM) -- uniform => scalar loads
    const int j = threadIdx.x;  // M col
    float acc = 0.f;
    #pragma unroll 8
    for (int r = 0; r < N; ++r) acc = fmaf(WK[r * N + i], WQ[r * N + j], acc);

    const int kk = i >> 5, q = (i >> 3) & 3, jj = i & 7;
    const int ct = j >> 4, n15 = j & 15;
    fragB[((kk * 8 + ct) * 64 + (q * 16 + n15)) * 8 + jj] = f2bf(acc);

    float sg = fabsf(1.0f / (1.0f + __expf(-acc)));
    float ws = wave_reduce(sg);
    __shared__ float red[2];
    if ((j & 63) == 0) red[j >> 6] = ws;
    __syncthreads();
    if (j == 0) atomicAdd(&out[1], red[0] + red[1]);
}

__global__ __launch_bounds__(TPB, 3) void main_kernel(
    const float* __restrict__ In, const unsigned short* __restrict__ fragB,
    float* __restrict__ out, float inv_denom) {
    __shared__ float F[BR * N];               // 32 KB DMA landing zone; wave w owns rows w*16..w*16+15
    __shared__ unsigned short sA[65][132];    // bf16 tile + boundary row; pad 132 (epilogue conflict-free)
    __shared__ float sRed[TPB / 64];

    const int tid = threadIdx.x;
    const int w = tid >> 6, lane = tid & 63;
    const int q = lane >> 4, n15 = lane & 15;

    // B fragments (wave's 32 output cols), held in VGPRs for the whole kernel
    bf16x8 bF[2][4];
    #pragma unroll
    for (int c = 0; c < 2; ++c)
        #pragma unroll
        for (int kk = 0; kk < 4; ++kk)
            bF[c][kk] = *(const bf16x8*)&fragB[((kk * 8 + (w * 2 + c)) * 64 + lane) * 8];

    bf16x8 bOne;   // all-ones B: rowsum via MFMA (C/D layout matches epilogue exactly)
    #pragma unroll
    for (int e = 0; e < 8; ++e) bOne[e] = (short)0x3F80;

    float lsum = 0.f;
    float4 x;            // boundary row (tile*64+64), wave 0 lanes 0..31

    auto issue = [&](int tile) {
        const float* gb = In + (size_t)tile * BR * N;
        #pragma unroll
        for (int j = 0; j < 8; ++j) {
            const int ci = w * 8 + j;                 // wave-private 1 KB chunks
            gld16(gb + ci * 256 + lane * 4, &F[ci * 256]);
        }
        long rX = (long)tile * BR + BR; if (rX > S_LEN - 1) rX = S_LEN - 1;
        if (tid < 32) x = *(const float4*)&In[rX * N + (tid << 2)];
    };

    int tile = blockIdx.x;
    bool first = true;
    issue(tile);                                   // prologue DMA, tile 0

    while (tile < NT) {
        const int next = tile + GRID;

        wait_vm0();                                // own DMA + x landed (F is wave-private!)
        const float4 xc = x;                       // consume-copy before next x load
        float4 r[8];
        #pragma unroll
        for (int t = 0; t < 8; ++t) {              // own 16 rows F -> regs
            const int row = w * 16 + t * 2 + (lane >> 5);
            r[t] = *(const float4*)&F[row * N + ((lane & 31) << 2)];
        }
        wait_lgkm0();                              // F reads complete -> F reusable
        if (next < NT) issue(next);                // DMA for next tile NOW, crosses barriers in flight

        if (!first) barrier_raw();                 // prev iter's sA readers done (no vmcnt drain!)
        #pragma unroll
        for (int t = 0; t < 8; ++t) {              // pack regs -> sA (own rows)
            const int row = w * 16 + t * 2 + (lane >> 5);
            *(uint2*)&sA[row][(lane & 31) << 2] =
                make_uint2(pack2bf(r[t].x, r[t].y), pack2bf(r[t].z, r[t].w));
        }
        if (tid < 32)
            *(uint2*)&sA[64][tid << 2] = make_uint2(pack2bf(xc.x, xc.y), pack2bf(xc.z, xc.w));
        barrier_raw();                             // sA ready for all (lgkm drained, vmcnt NOT)

        // MFMA: z-tiles + rowsum in one pass
        f32x4 acc[4][2], accRS[4];
        #pragma unroll
        for (int rt = 0; rt < 4; ++rt) {
            accRS[rt] = (f32x4){0.f, 0.f, 0.f, 0.f};
            #pragma unroll
            for (int c = 0; c < 2; ++c) acc[rt][c] = (f32x4){0.f, 0.f, 0.f, 0.f};
        }
        #pragma unroll
        for (int rt = 0; rt < 4; ++rt) {
            #pragma unroll
            for (int kk = 0; kk < 4; ++kk) {
                bf16x8 a = *(const bf16x8*)&sA[rt * 16 + n15][kk * 32 + q * 8];
                accRS[rt] = __builtin_amdgcn_mfma_f32_16x16x32_bf16(a, bOne, accRS[rt], 0, 0, 0);
                #pragma unroll
                for (int c = 0; c < 2; ++c)
                    acc[rt][c] = __builtin_amdgcn_mfma_f32_16x16x32_bf16(a, bF[c][kk], acc[rt][c], 0, 0, 0);
            }
        }

        // epilogue: C/D row = rt*16 + q*4 + reg, col = w*32 + c*16 + n15
        const long r0 = (long)tile * BR;
        #pragma unroll
        for (int rt = 0; rt < 4; ++rt) {
            #pragma unroll
            for (int reg = 0; reg < 4; ++reg) {
                const int row = rt * 16 + q * 4 + reg;
                const float rs = accRS[rt][reg];
                const long s = r0 + row;
                const bool has = (s < S_LEN - 1);
                #pragma unroll
                for (int c = 0; c < 2; ++c) {
                    const float z = acc[rt][c][reg];
                    const float sp = fmaxf(z, 0.f) + __logf(1.0f + __expf(-fabsf(z)));
                    const float o = sp * rs;
                    if (has) {
                        const int col = w * 32 + c * 16 + n15;
                        const float d = o - bf2f(sA[row + 1][col]);
                        lsum = fmaf(d, d, lsum);
                    }
                }
            }
        }
        // epilogue ds_reads drained by next iteration's barrier_raw (lgkmcnt(0)) before sA overwrite
        tile = next;
        first = false;
    }

    const float wsum = wave_reduce(lsum);
    if ((tid & 63) == 0) sRed[w] = wsum;
    __syncthreads();
    if (tid == 0) {
        float t = 0.f;
        #pragma unroll
        for (int w2 = 0; w2 < TPB / 64; ++w2) t += sRed[w2];
        atomicAdd(&out[0], t * inv_denom);
    }
}

extern "C" void kernel_launch(void* const* d_in, const int* in_sizes, int n_in,
                              void* d_out, int out_size, void* d_ws, size_t ws_size,
                              hipStream_t stream) {
    const float* In = (const float*)d_in[0];
    const float* WQ = (const float*)d_in[1];
    const float* WK = (const float*)d_in[2];
    float* out = (float*)d_out;
    unsigned short* fragB = (unsigned short*)d_ws;   // 32 KB

    hipMemsetAsync(d_out, 0, 2 * sizeof(float), stream);
    mk_kernel<<<128, 128, 0, stream>>>(WQ, WK, fragB, out);
    const float inv = (float)(1.0 / ((double)(S_LEN - 1) * (double)N));
    main_kernel<<<GRID, TPB, 0, stream>>>(In, fragB, out, inv);
}

// Round 8
// 205.161 us; speedup vs baseline: 1.3816x; 1.0420x over previous
//
#include <hip/hip_runtime.h>
#include <math.h>

#define S_LEN 262144
#define N 128
#define TPB 256
#define GRID 768
#define NWAVES (GRID * 4)          // 3072 waves
#define ITEMS (S_LEN / 16 * 2)     // strip(16 rows) x col-half = 32768 items

typedef __attribute__((ext_vector_type(8))) short bf16x8;
typedef __attribute__((ext_vector_type(4))) float f32x4;

__device__ __forceinline__ unsigned short f2bf(float x) {
    unsigned b = __float_as_uint(x);
    b = (b + 0x7FFF + ((b >> 16) & 1)) >> 16;   // RNE to bf16
    return (unsigned short)b;
}
__device__ __forceinline__ float bf2f(unsigned short u) {
    return __uint_as_float((unsigned)u << 16);
}
// low16 = bf16(x), high16 = bf16(y) (round-half-up): 2 adds + 1 perm
__device__ __forceinline__ unsigned pack2bf(float x, float y) {
    return __builtin_amdgcn_perm(__float_as_uint(y) + 0x8000u,
                                 __float_as_uint(x) + 0x8000u, 0x07060302u);
}
__device__ __forceinline__ float wave_reduce(float v) {
    #pragma unroll
    for (int off = 32; off > 0; off >>= 1) v += __shfl_down(v, off, 64);
    return v;
}
// intra-wave LDS ordering fence: drain DS queue + stop compiler reordering.
// Does NOT touch vmcnt (global loads stay in flight) and is NOT a barrier.
__device__ __forceinline__ void lds_fence() {
    asm volatile("s_waitcnt lgkmcnt(0)" ::: "memory");
}

// M = W_K^T @ W_Q (128x128) fp32; emit bf16 in MFMA-B-fragment order:
//   frag[((kk*8 + ct)*64 + lane)*8 + j] = M[kk*32 + (lane>>4)*8 + j][ct*16 + (lane&15)]
// l1 = sum(sigmoid(M)) -> out[1].
__global__ void mk_kernel(const float* __restrict__ WQ, const float* __restrict__ WK,
                          unsigned short* __restrict__ fragB, float* __restrict__ out) {
    const int i = blockIdx.x;   // M row (k of main GEMM) -- uniform => scalar loads
    const int j = threadIdx.x;  // M col
    float acc = 0.f;
    #pragma unroll 8
    for (int r = 0; r < N; ++r) acc = fmaf(WK[r * N + i], WQ[r * N + j], acc);

    const int kk = i >> 5, q = (i >> 3) & 3, jj = i & 7;
    const int ct = j >> 4, n15 = j & 15;
    fragB[((kk * 8 + ct) * 64 + (q * 16 + n15)) * 8 + jj] = f2bf(acc);

    float sg = fabsf(1.0f / (1.0f + __expf(-acc)));
    float ws = wave_reduce(sg);
    __shared__ float red[2];
    if ((j & 63) == 0) red[j >> 6] = ws;
    __syncthreads();
    if (j == 0) atomicAdd(&out[1], red[0] + red[1]);
}

// Wave-autonomous: each wave owns (strip of 16 rows) x (64 cols). No cross-wave
// barriers in the main loop; per-wave private LDS strip; global loads straight
// to VGPRs; intra-wave lgkm fences order the LDS round-trip.
__global__ __launch_bounds__(TPB, 3) void main_kernel(
    const float* __restrict__ In, const unsigned short* __restrict__ fragB,
    float* __restrict__ out, float inv_denom) {
    __shared__ unsigned short sA[4][17][132];   // per-wave strip: 16 rows + boundary row
    __shared__ float sRed[4];

    const int tid = threadIdx.x;
    const int w = tid >> 6, lane = tid & 63;
    const int q = lane >> 4, n15 = lane & 15;
    const int gid = blockIdx.x * 4 + w;          // global wave id
    const int half = gid & 1;                    // col half (item stride is even)

    // B fragments for this wave's 64 cols (ct = half*4 + c4), constant all kernel
    bf16x8 bF[4][4];
    #pragma unroll
    for (int c4 = 0; c4 < 4; ++c4)
        #pragma unroll
        for (int kk = 0; kk < 4; ++kk)
            bF[c4][kk] = *(const bf16x8*)&fragB[((kk * 8 + (half * 4 + c4)) * 64 + lane) * 8];

    bf16x8 bOne;   // all-ones B: rowsum via MFMA, C/D layout matches epilogue
    #pragma unroll
    for (int e = 0; e < 8; ++e) bOne[e] = (short)0x3F80;

    unsigned short (*my)[132] = sA[w];
    float lsum = 0.f;
    float4 r[8];
    float2 x;

    auto issue = [&](int item) {
        const long r0 = (long)(item >> 1) * 16;
        const float* base = In + r0 * N;
        #pragma unroll
        for (int j = 0; j < 8; ++j)              // 8 x 1KB chunks: rows 2j, 2j+1
            r[j] = *(const float4*)(base + j * 256 + lane * 4);
        long rX = r0 + 16; if (rX > S_LEN - 1) rX = S_LEN - 1;
        x = *(const float2*)&In[rX * N + lane * 2];   // boundary row, all 64 lanes
    };

    int item = gid;
    issue(item);

    while (item < ITEMS) {
        const int next = item + NWAVES;

        // pack fp32 regs -> bf16 LDS strip (compiler inserts vmcnt waits for r/x)
        #pragma unroll
        for (int j = 0; j < 8; ++j) {
            const int row = 2 * j + (lane >> 5);
            const int c = lane & 31;
            *(unsigned int*)&my[row][c * 4] = pack2bf(r[j].x, r[j].y);
            *(unsigned int*)&my[row][c * 4 + 2] = pack2bf(r[j].z, r[j].w);
        }
        *(unsigned int*)&my[16][lane * 2] = pack2bf(x.x, x.y);

        // immediately put next item's loads in flight (r, x now dead)
        if (next < ITEMS) issue(next);

        lds_fence();   // pack visible to all lanes of this wave before fragment reads

        // MFMA: z (4 col-tiles) + rowsum, K=128
        f32x4 acc[4], aRS;
        aRS = (f32x4){0.f, 0.f, 0.f, 0.f};
        #pragma unroll
        for (int c4 = 0; c4 < 4; ++c4) acc[c4] = (f32x4){0.f, 0.f, 0.f, 0.f};
        #pragma unroll
        for (int kk = 0; kk < 4; ++kk) {
            bf16x8 a = *(const bf16x8*)&my[n15][kk * 32 + q * 8];  // A[m=n15][k=q*8+j]
            aRS = __builtin_amdgcn_mfma_f32_16x16x32_bf16(a, bOne, aRS, 0, 0, 0);
            #pragma unroll
            for (int c4 = 0; c4 < 4; ++c4)
                acc[c4] = __builtin_amdgcn_mfma_f32_16x16x32_bf16(a, bF[c4][kk], acc[c4], 0, 0, 0);
        }

        // epilogue: C/D row = q*4+reg, col = n15 (per 16-tile)
        const long r0 = (long)(item >> 1) * 16;
        #pragma unroll
        for (int reg = 0; reg < 4; ++reg) {
            const int row = q * 4 + reg;
            const float rs = aRS[reg];
            const long s = r0 + row;
            const bool has = (s < S_LEN - 1);
            #pragma unroll
            for (int c4 = 0; c4 < 4; ++c4) {
                const float z = acc[c4][reg];
                const float sp = fmaxf(z, 0.f) + __logf(1.0f + __expf(-fabsf(z)));
                const float o = sp * rs;
                if (has) {
                    const int col = half * 64 + c4 * 16 + n15;
                    const float d = o - bf2f(my[row + 1][col]);
                    lsum = fmaf(d, d, lsum);
                }
            }
        }

        lds_fence();   // epilogue LDS reads done before next iteration's pack overwrites
        item = next;
    }

    const float wsum = wave_reduce(lsum);
    if ((tid & 63) == 0) sRed[w] = wsum;
    __syncthreads();
    if (tid == 0) {
        float t = 0.f;
        #pragma unroll
        for (int w2 = 0; w2 < 4; ++w2) t += sRed[w2];
        atomicAdd(&out[0], t * inv_denom);
    }
}

extern "C" void kernel_launch(void* const* d_in, const int* in_sizes, int n_in,
                              void* d_out, int out_size, void* d_ws, size_t ws_size,
                              hipStream_t stream) {
    const float* In = (const float*)d_in[0];
    const float* WQ = (const float*)d_in[1];
    const float* WK = (const float*)d_in[2];
    float* out = (float*)d_out;
    unsigned short* fragB = (unsigned short*)d_ws;   // 32 KB

    hipMemsetAsync(d_out, 0, 2 * sizeof(float), stream);
    mk_kernel<<<128, 128, 0, stream>>>(WQ, WK, fragB, out);
    const float inv = (float)(1.0 / ((double)(S_LEN - 1) * (double)N));
    main_kernel<<<GRID, TPB, 0, stream>>>(In, fragB, out, inv);
}